// Round 3
// baseline (808.520 us; speedup 1.0000x reference)
//
#include <hip/hip_runtime.h>
#include <math.h>

#define PI_F 3.14159265358979323846f

__constant__ float c_pkva[12] = {
  -0.0144f, 0.0272f, -0.0526f, 0.0972f, -0.193f, 0.63f,
   0.63f, -0.193f, 0.0972f, -0.0526f, 0.0272f, -0.0144f
};

constexpr int ilog2c(int n) { int l = 0; while (n > 1) { n >>= 1; ++l; } return l; }
constexpr int fft_nt(int N) { return (N >= 512) ? N / 8 : N / 4; }

__device__ __forceinline__ float phi_dev(int k, int n) {
  int kk = (k < n - k) ? k : (n - k);
  float w = 2.0f * PI_F * (float)kk / (float)n;
  float s = (w - PI_F / 3.0f) * (3.0f / PI_F);
  s = fminf(fmaxf(s, 0.0f), 1.0f);
  float s2 = s * s;
  float beta = s2 * s2 * (35.0f - 84.0f * s + 70.0f * s2 - 20.0f * s2 * s);
  return __cosf(0.5f * PI_F * beta);
}

__device__ __forceinline__ float2 cmul(float2 a, float2 b) {
  return make_float2(a.x * b.x - a.y * b.y, a.x * b.y + a.y * b.x);
}
__device__ __forceinline__ float2 cadd(float2 a, float2 b) { return make_float2(a.x + b.x, a.y + b.y); }
__device__ __forceinline__ float2 csub(float2 a, float2 b) { return make_float2(a.x - b.x, a.y - b.y); }

// ---------------------------------------------------------------------------
// In-LDS Stockham FFT core. Radix-8 (NT == N/8, N>=512) with optional lead
// radix-2; radix-4 path (NT == N/4) for small N. Caller syncs after filling
// sbuf[cur]. Takes and returns the ping-pong buffer index.
// ---------------------------------------------------------------------------
template <int N, int NT>
__device__ __forceinline__ int fft_core(float2 (*sbuf)[N], float dirsign, int tid, int cur) {
  constexpr int LOG2 = ilog2c(N);
  if constexpr (NT == N / 8) {
    constexpr int REM = LOG2 % 3;
    if constexpr (REM == 1) {  // lead radix-2, conflict-free float4 store
#pragma unroll
      for (int j = tid; j < N / 2; j += NT) {
        float2 v0 = sbuf[cur][j], v1 = sbuf[cur][j + N / 2];
        float2 e = cadd(v0, v1), o = csub(v0, v1);
        *(float4*)&sbuf[cur ^ 1][2 * j] = make_float4(e.x, e.y, o.x, o.y);
      }
      cur ^= 1;
      __syncthreads();
    } else if constexpr (REM == 2) {  // lead radix-4 (Ns=1)
#pragma unroll
      for (int j = tid; j < N / 4; j += NT) {
        float2 v0 = sbuf[cur][j], v1 = sbuf[cur][j + N / 4];
        float2 v2 = sbuf[cur][j + N / 2], v3 = sbuf[cur][j + 3 * (N / 4)];
        float2 a0 = cadd(v0, v2), a1 = csub(v0, v2);
        float2 a2 = cadd(v1, v3), a3 = csub(v1, v3);
        float2 r1 = make_float2(-dirsign * a3.y, dirsign * a3.x);
        sbuf[cur ^ 1][4 * j]     = cadd(a0, a2);
        sbuf[cur ^ 1][4 * j + 1] = cadd(a1, r1);
        sbuf[cur ^ 1][4 * j + 2] = csub(a0, a2);
        sbuf[cur ^ 1][4 * j + 3] = csub(a1, r1);
      }
      cur ^= 1;
      __syncthreads();
    }
    constexpr int START = (REM == 1) ? 2 : ((REM == 2) ? 4 : 1);
#pragma unroll
    for (int Ns = START; Ns < N; Ns <<= 3) {
      const int j = tid;
      const int base = j & (Ns - 1);
      float ang = dirsign * (2.0f * PI_F) * (float)base / (float)(8 * Ns);
      float2 w1; __sincosf(ang, &w1.y, &w1.x);
      float2 w2 = cmul(w1, w1);
      float2 w3 = cmul(w2, w1);
      float2 w4 = cmul(w2, w2);
      float2 w5 = cmul(w3, w2);
      float2 w6 = cmul(w3, w3);
      float2 w7 = cmul(w4, w3);
      float2 u0 = sbuf[cur][j];
      float2 u1 = cmul(sbuf[cur][j + (N / 8)], w1);
      float2 u2 = cmul(sbuf[cur][j + 2 * (N / 8)], w2);
      float2 u3 = cmul(sbuf[cur][j + 3 * (N / 8)], w3);
      float2 u4 = cmul(sbuf[cur][j + 4 * (N / 8)], w4);
      float2 u5 = cmul(sbuf[cur][j + 5 * (N / 8)], w5);
      float2 u6 = cmul(sbuf[cur][j + 6 * (N / 8)], w6);
      float2 u7 = cmul(sbuf[cur][j + 7 * (N / 8)], w7);
      // even FFT4 (u0,u2,u4,u6)
      float2 a0 = cadd(u0, u4), a1 = csub(u0, u4);
      float2 a2 = cadd(u2, u6), a3 = csub(u2, u6);
      float2 ra = make_float2(-dirsign * a3.y, dirsign * a3.x);
      float2 e0 = cadd(a0, a2), e1 = cadd(a1, ra), e2 = csub(a0, a2), e3 = csub(a1, ra);
      // odd FFT4 (u1,u3,u5,u7)
      float2 b0 = cadd(u1, u5), b1 = csub(u1, u5);
      float2 b2 = cadd(u3, u7), b3 = csub(u3, u7);
      float2 rb = make_float2(-dirsign * b3.y, dirsign * b3.x);
      float2 o0 = cadd(b0, b2), o1 = cadd(b1, rb), o2 = csub(b0, b2), o3 = csub(b1, rb);
      // twiddle odds by w8^m, w8 = (C, dirsign*C)
      const float C8 = 0.70710678118654752f;
      o1 = make_float2(C8 * (o1.x - dirsign * o1.y), C8 * (dirsign * o1.x + o1.y));
      o2 = make_float2(-dirsign * o2.y, dirsign * o2.x);
      o3 = make_float2(-C8 * (o3.x + dirsign * o3.y), C8 * (dirsign * o3.x - o3.y));
      int idxD = ((j - base) << 3) + base;
      cur ^= 1;
      sbuf[cur][idxD]          = cadd(e0, o0);
      sbuf[cur][idxD + Ns]     = cadd(e1, o1);
      sbuf[cur][idxD + 2 * Ns] = cadd(e2, o2);
      sbuf[cur][idxD + 3 * Ns] = cadd(e3, o3);
      sbuf[cur][idxD + 4 * Ns] = csub(e0, o0);
      sbuf[cur][idxD + 5 * Ns] = csub(e1, o1);
      sbuf[cur][idxD + 6 * Ns] = csub(e2, o2);
      sbuf[cur][idxD + 7 * Ns] = csub(e3, o3);
      __syncthreads();
    }
  } else {
    // radix-4 path, NT == N/4
    constexpr bool LEAD2 = (LOG2 & 1);
    if constexpr (LEAD2) {
#pragma unroll
      for (int j = tid; j < N / 2; j += NT) {
        float2 v0 = sbuf[cur][j], v1 = sbuf[cur][j + N / 2];
        float2 e = cadd(v0, v1), o = csub(v0, v1);
        *(float4*)&sbuf[cur ^ 1][2 * j] = make_float4(e.x, e.y, o.x, o.y);
      }
      cur ^= 1;
      __syncthreads();
    }
#pragma unroll
    for (int Ns = LEAD2 ? 2 : 1; Ns < N; Ns <<= 2) {
      int j = tid;
      int base = j & (Ns - 1);
      float ang = dirsign * (2.0f * PI_F) * (float)base / (float)(4 * Ns);
      float2 w1; __sincosf(ang, &w1.y, &w1.x);
      float2 w2 = cmul(w1, w1);
      float2 w3 = cmul(w2, w1);
      float2 v0 = sbuf[cur][j];
      float2 v1 = cmul(sbuf[cur][j + N / 4], w1);
      float2 v2 = cmul(sbuf[cur][j + N / 2], w2);
      float2 v3 = cmul(sbuf[cur][j + 3 * (N / 4)], w3);
      float2 a0 = cadd(v0, v2), a1 = csub(v0, v2);
      float2 a2 = cadd(v1, v3), a3 = csub(v1, v3);
      float2 r1 = make_float2(-dirsign * a3.y, dirsign * a3.x);
      int idxD = ((j - base) << 2) + base;
      cur ^= 1;
      sbuf[cur][idxD]          = cadd(a0, a2);
      sbuf[cur][idxD + Ns]     = cadd(a1, r1);
      sbuf[cur][idxD + 2 * Ns] = csub(a0, a2);
      sbuf[cur][idxD + 3 * Ns] = csub(a1, r1);
      __syncthreads();
    }
  }
  return cur;
}

// ---------------------------------------------------------------------------
// Batched row FFT. LMODE: 1 = complex load, 2 = complex * Hm mask.
// SMODE: 0 = complex store, 1 = real store.
// ---------------------------------------------------------------------------
template <int N, int LMODE, int SMODE>
__global__ void __launch_bounds__(fft_nt(N))
fft_rows_k(const void* __restrict__ vin, void* __restrict__ vout,
           float dirsign, float scale) {
  constexpr int NT = fft_nt(N);
  __shared__ __align__(16) float2 sbuf[2][N];
  const int tid = threadIdx.x;
  const int row = blockIdx.x;
  const int r = row & (N - 1);

  if (LMODE == 1) {
    const float2* in = (const float2*)vin;
#pragma unroll
    for (int i = tid; i < N; i += NT) {
      float2 v = in[(size_t)row * N + i];
      sbuf[0][i] = make_float2(v.x * scale, v.y * scale);
    }
  } else {
    const float2* in = (const float2*)vin;
    float pr = phi_dev(r, N);
#pragma unroll
    for (int i = tid; i < N; i += NT) {
      float lm = pr * phi_dev(i, N);
      float hm = sqrtf(fmaxf(1.0f - lm * lm, 0.0f));
      float m = hm * scale;
      float2 v = in[(size_t)row * N + i];
      sbuf[0][i] = make_float2(v.x * m, v.y * m);
    }
  }
  __syncthreads();

  int cur = fft_core<N, NT>(sbuf, dirsign, tid, 0);

  if (SMODE == 0) {
    float2* outp = (float2*)vout;
#pragma unroll
    for (int i = tid; i < N; i += NT)
      outp[(size_t)row * N + i] = sbuf[cur][i];
  } else {
    float* outp = (float*)vout;
#pragma unroll
    for (int i = tid; i < N; i += NT)
      outp[(size_t)row * N + i] = sbuf[cur][i].x;
  }
}

// ---------------------------------------------------------------------------
// First forward FFT on real input: rows (2r, 2r+1) packed as one complex FFT,
// untangled via Hermitian symmetry.
// ---------------------------------------------------------------------------
template <int N>
__global__ void __launch_bounds__(fft_nt(N))
rfft_pairs_k(const float* __restrict__ in, float2* __restrict__ out) {
  constexpr int NT = fft_nt(N);
  __shared__ __align__(16) float2 sbuf[2][N];
  const int tid = threadIdx.x;
  const int img = blockIdx.x >> (ilog2c(N) - 1);
  const int r = blockIdx.x & (N / 2 - 1);
  const size_t row0 = (size_t)img * N + 2 * r;
  const float* p0 = in + row0 * N;
  const float* p1 = p0 + N;

#pragma unroll
  for (int i = tid; i < N; i += NT)
    sbuf[0][i] = make_float2(p0[i], p1[i]);
  __syncthreads();

  int cur = fft_core<N, NT>(sbuf, -1.0f, tid, 0);

  float2* o0 = out + row0 * N;
  float2* o1 = o0 + N;
#pragma unroll
  for (int i = tid; i < N; i += NT) {
    float2 Z = sbuf[cur][i];
    float2 Zr = sbuf[cur][(N - i) & (N - 1)];
    float2 Zc = make_float2(Zr.x, -Zr.y);
    o0[i] = make_float2(0.5f * (Z.x + Zc.x), 0.5f * (Z.y + Zc.y));
    float2 dd = make_float2(Z.x - Zc.x, Z.y - Zc.y);
    o1[i] = make_float2(0.5f * dd.y, -0.5f * dd.x);
  }
}

// ---------------------------------------------------------------------------
// Fused level-1 column pass: forward FFT along ky, store spectrum row (for
// alias), apply Hm*(1/N) in LDS, inverse FFT along ky, store in-place.
// inout = bufB rows [img, kx, r]; spec = bufA gets X^T.
// ---------------------------------------------------------------------------
template <int N>
__global__ void __launch_bounds__(fft_nt(N))
fft_col_fused_k(float2* __restrict__ inout, float2* __restrict__ spec) {
  constexpr int NT = fft_nt(N);
  __shared__ __align__(16) float2 sbuf[2][N];
  const int tid = threadIdx.x;
  const int row = blockIdx.x;
  const int r = row & (N - 1);  // kx

#pragma unroll
  for (int i = tid; i < N; i += NT)
    sbuf[0][i] = inout[(size_t)row * N + i];
  __syncthreads();

  int cur = fft_core<N, NT>(sbuf, -1.0f, tid, 0);

  float pr = phi_dev(r, N);
#pragma unroll
  for (int i = tid; i < N; i += NT) {
    float2 v = sbuf[cur][i];
    spec[(size_t)row * N + i] = v;
    float lm = pr * phi_dev(i, N);
    float hm = sqrtf(fmaxf(1.0f - lm * lm, 0.0f)) * (1.0f / (float)N);
    sbuf[cur][i] = make_float2(v.x * hm, v.y * hm);
  }
  __syncthreads();

  cur = fft_core<N, NT>(sbuf, 1.0f, tid, cur);

#pragma unroll
  for (int i = tid; i < N; i += NT)
    inout[(size_t)row * N + i] = sbuf[cur][i];
}

// ---------------------------------------------------------------------------
// Fused: inverse row FFT + first DFB fan split (axis=-1), with deinterleaved
// coset scratch to kill LDS bank conflicts in the tap loops.
// ---------------------------------------------------------------------------
template <int N>
__global__ void __launch_bounds__(fft_nt(N))
ifft_fan_k(const float2* __restrict__ in, float* __restrict__ outb,
           float scale, int halfT) {
  constexpr int NT = fft_nt(N);
  constexpr int W2 = N / 2;
  __shared__ __align__(16) float2 sbuf[2][N];
  const int tid = threadIdx.x;
  const int nr = blockIdx.x;
  const int r = nr & (N - 1);
  const int par = r & 1;
  const float sgn = par ? -1.0f : 1.0f;

#pragma unroll
  for (int i = tid; i < N; i += NT) {
    float2 v = in[(size_t)nr * N + i];
    sbuf[0][i] = make_float2(v.x * scale, v.y * scale);
  }
  __syncthreads();

  int cur = fft_core<N, NT>(sbuf, 1.0f, tid, 0);

  // Deinterleave cosets into stride-1 float scratch (idle ping-pong buffer).
  float* scratch = (float*)sbuf[cur ^ 1];
  float* xe = scratch;            // W2 floats
  float* xo = scratch + W2;       // W2 floats
  float* db = scratch + 2 * W2;   // W2 floats  (3*W2 <= 2*N floats)
#pragma unroll
  for (int j = tid; j < W2; j += NT) {
    xe[j] = sbuf[cur][(2 * j + par) & (N - 1)].x;
    xo[j] = sbuf[cur][(2 * j + 1 + par) & (N - 1)].x;
  }
  __syncthreads();

  float* outs = outb + (size_t)nr * W2;
  float* outd = outb + halfT + (size_t)nr * W2;
#pragma unroll 2
  for (int j = tid; j < W2; j += NT) {
    float acc = 0.0f;
#pragma unroll
    for (int k = 0; k < 12; k++)
      acc += c_pkva[k] * xe[(j - 6 + k + W2) & (W2 - 1)];
    float dv = sgn * (xo[j] - acc);
    db[j] = dv;
    outd[j] = dv;
  }
  __syncthreads();
#pragma unroll 2
  for (int j = tid; j < W2; j += NT) {
    float acc = 0.0f;
#pragma unroll
    for (int k = 0; k < 12; k++)
      acc += c_pkva[k] * db[(j - 6 + k + W2) & (W2 - 1)];
    outs[j] = sgn * xe[j] + 0.5f * acc;
  }
}

// Batched square transpose (per-image), complex
__global__ void transpose_k(const float2* __restrict__ in,
                            float2* __restrict__ out, int N) {
  __shared__ float2 tile[32][33];
  int img = blockIdx.z;
  size_t base = (size_t)img * N * N;
  int x = blockIdx.x * 32 + threadIdx.x;
  int y0 = blockIdx.y * 32;
  for (int j = threadIdx.y; j < 32; j += 8)
    tile[j][threadIdx.x] = in[base + (size_t)(y0 + j) * N + x];
  __syncthreads();
  int x2 = blockIdx.y * 32 + threadIdx.x;
  int y2 = blockIdx.x * 32;
  for (int j = threadIdx.y; j < 32; j += 8)
    out[base + (size_t)(y2 + j) * N + x2] = tile[threadIdx.x][j];
}

// Frequency-domain decimation by 2 with Lm mask (transposed spectra ok).
__global__ void alias_k(const float2* __restrict__ in, float2* __restrict__ out,
                        int N, int lgN2) {
  int idx = blockIdx.x * 256 + threadIdx.x;
  int N2 = N >> 1;
  int c = idx & (N2 - 1);
  int r = (idx >> lgN2) & (N2 - 1);
  int img = idx >> (2 * lgN2);
  float pr0 = phi_dev(r, N), pr1 = phi_dev(r + N2, N);
  float pc0 = phi_dev(c, N), pc1 = phi_dev(c + N2, N);
  size_t base = (size_t)img * N * N;
  float2 v00 = in[base + (size_t)r * N + c];
  float2 v01 = in[base + (size_t)r * N + c + N2];
  float2 v10 = in[base + (size_t)(r + N2) * N + c];
  float2 v11 = in[base + (size_t)(r + N2) * N + c + N2];
  float m00 = pr0 * pc0, m01 = pr0 * pc1, m10 = pr1 * pc0, m11 = pr1 * pc1;
  float2 o;
  o.x = 0.25f * (v00.x * m00 + v01.x * m01 + v10.x * m10 + v11.x * m11);
  o.y = 0.25f * (v00.y * m00 + v01.y * m01 + v10.y * m10 + v11.y * m11);
  out[((size_t)img << (2 * lgN2)) + ((size_t)r << lgN2) + c] = o;
}

// Standalone DFB fan split, axis=-1 (mid-pipeline; W <= 512 here).
__global__ void __launch_bounds__(256)
fs_row_k(const float* __restrict__ x, float* __restrict__ outb,
         int lgH, int lgW, int halfT) {
  __shared__ float xe[512], xo[512], db[512];
  int H = 1 << lgH, W = 1 << lgW, W2 = W >> 1;
  int nr = blockIdx.x;
  int r = nr & (H - 1);
  int par = r & 1;
  float sgn = par ? -1.0f : 1.0f;
  const float* xrow = x + (size_t)nr * W;
  for (int j = threadIdx.x; j < W2; j += 256) {
    xe[j] = sgn * xrow[(2 * j + par) & (W - 1)];
    xo[j] = sgn * xrow[(2 * j + 1 + par) & (W - 1)];
  }
  __syncthreads();
  float* outs = outb + (size_t)nr * W2;
  float* outd = outb + halfT + (size_t)nr * W2;
  for (int j = threadIdx.x; j < W2; j += 256) {
    float acc = 0.0f;
#pragma unroll
    for (int k = 0; k < 12; k++)
      acc += c_pkva[k] * xe[(j - 6 + k + W2) & (W2 - 1)];
    float dv = xo[j] - acc;
    db[j] = dv;
    outd[j] = dv;
  }
  __syncthreads();
  for (int j = threadIdx.x; j < W2; j += 256) {
    float acc = 0.0f;
#pragma unroll
    for (int k = 0; k < 12; k++)
      acc += c_pkva[k] * db[(j - 6 + k + W2) & (W2 - 1)];
    outs[j] = xe[j] + 0.5f * acc;
  }
}

// DFB fan split, axis=-2: d pass.
__global__ void __launch_bounds__(256)
fs_col_d_k(const float* __restrict__ x, float* __restrict__ outb,
           int lgH, int lgW, int halfT) {
  int H = 1 << lgH, W = 1 << lgW, H2 = H >> 1;
  int idx = blockIdx.x * 256 + threadIdx.x;
  int c = idx & (W - 1);
  int i = (idx >> lgW) & (H2 - 1);
  int n = idx >> (lgW + lgH - 1);
  int par = c & 1;
  float sgn = par ? -1.0f : 1.0f;
  const float* xim = x + ((size_t)n << (lgH + lgW));
  float p1 = xim[(((2 * i + 1 + par) & (H - 1)) << lgW) + c];
  float acc = 0.0f;
#pragma unroll
  for (int k = 0; k < 12; k++) {
    int m = (i - 6 + k + H2) & (H2 - 1);
    acc += c_pkva[k] * xim[(((2 * m + par) & (H - 1)) << lgW) + c];
  }
  outb[halfT + idx] = sgn * (p1 - acc);
}

// DFB fan split, axis=-2: s pass.
__global__ void __launch_bounds__(256)
fs_col_s_k(const float* __restrict__ x, float* __restrict__ outb,
           int lgH, int lgW, int halfT) {
  int H = 1 << lgH, W = 1 << lgW, H2 = H >> 1;
  int idx = blockIdx.x * 256 + threadIdx.x;
  int c = idx & (W - 1);
  int i = (idx >> lgW) & (H2 - 1);
  int n = idx >> (lgW + lgH - 1);
  int par = c & 1;
  float sgn = par ? -1.0f : 1.0f;
  const float* xim = x + ((size_t)n << (lgH + lgW));
  float p0 = sgn * xim[(((2 * i + par) & (H - 1)) << lgW) + c];
  float acc = 0.0f;
#pragma unroll
  for (int k = 0; k < 12; k++) {
    int m = (i - 6 + k + H2) & (H2 - 1);
    acc += c_pkva[k] * outb[halfT + ((((n << (lgH - 1)) + m) << lgW) + c)];
  }
  outb[idx] = p0 + 0.5f * acc;
}

__global__ void fill_err_k(float* out) {
  out[threadIdx.x] = 1.0e9f;
}

// ---------------------------------------------------------------------------
extern "C" void kernel_launch(void* const* d_in, const int* in_sizes, int n_in,
                              void* d_out, int out_size, void* d_ws, size_t ws_size,
                              hipStream_t stream) {
  const float* x = (const float*)d_in[0];
  float* out = (float*)d_out;
  char* ws = (char*)d_ws;

  const size_t NEED = 312475648ull;
  if (ws_size < NEED) {
    fill_err_k<<<dim3(1), dim3(256), 0, stream>>>(out);
    return;
  }

  float2* bufA  = (float2*)(ws);
  float2* bufB  = (float2*)(ws + 134217728);
  float2* spec2 = (float2*)(ws + 268435456);
  float2* spec3 = (float2*)(ws + 301989888);
  float2* spec4 = (float2*)(ws + 310378496);

  float* out0 = out;             // 262144
  float* out1 = out + 262144;    // 1048576
  float* out2 = out + 1310720;   // 4194304
  float* out3 = out + 5505024;   // 16777216

  // ---- Level 1
  rfft_pairs_k<1024><<<dim3(8192), dim3(128), 0, stream>>>(x, bufA);
  transpose_k<<<dim3(32, 32, 16), dim3(32, 8), 0, stream>>>(bufA, bufB, 1024);
  // fwd col FFT -> bufA = X^T; Hm * inverse col FFT in-place in bufB
  fft_col_fused_k<1024><<<dim3(16384), dim3(128), 0, stream>>>(bufB, bufA);
  alias_k<<<dim3(16384), dim3(256), 0, stream>>>(bufA, spec2, 1024, 9);
  transpose_k<<<dim3(32, 32, 16), dim3(32, 8), 0, stream>>>(bufB, bufA, 1024);
  ifft_fan_k<1024><<<dim3(16384), dim3(128), 0, stream>>>(bufA, (float*)bufB, 1.0f / 1024.0f, 8388608);
  // DFB n=4 remaining stages
  fs_col_d_k<<<dim3(32768), dim3(256), 0, stream>>>((float*)bufB, (float*)bufA, 10, 9, 8388608);
  fs_col_s_k<<<dim3(32768), dim3(256), 0, stream>>>((float*)bufB, (float*)bufA, 10, 9, 8388608);
  fs_row_k  <<<dim3(32768), dim3(256), 0, stream>>>((float*)bufA, (float*)bufB, 9, 9, 8388608);
  fs_col_d_k<<<dim3(32768), dim3(256), 0, stream>>>((float*)bufB, out3, 9, 8, 8388608);
  fs_col_s_k<<<dim3(32768), dim3(256), 0, stream>>>((float*)bufB, out3, 9, 8, 8388608);

  // ---- Level 2
  alias_k<<<dim3(4096), dim3(256), 0, stream>>>(spec2, spec3, 512, 8);
  fft_rows_k<512, 2, 0><<<dim3(8192), dim3(64), 0, stream>>>((const void*)spec2, (void*)bufA, 1.0f, 1.0f / 512.0f);
  transpose_k<<<dim3(16, 16, 16), dim3(32, 8), 0, stream>>>(bufA, bufB, 512);
  ifft_fan_k<512><<<dim3(8192), dim3(64), 0, stream>>>(bufB, (float*)bufA, 1.0f / 512.0f, 2097152);
  fs_col_d_k<<<dim3(8192),  dim3(256), 0, stream>>>((float*)bufA, (float*)bufB, 9, 8, 2097152);
  fs_col_s_k<<<dim3(8192),  dim3(256), 0, stream>>>((float*)bufA, (float*)bufB, 9, 8, 2097152);
  fs_row_k  <<<dim3(16384), dim3(256), 0, stream>>>((float*)bufB, out2, 8, 8, 2097152);

  // ---- Level 3
  alias_k<<<dim3(1024), dim3(256), 0, stream>>>(spec3, spec4, 256, 7);
  fft_rows_k<256, 2, 0><<<dim3(4096), dim3(64), 0, stream>>>((const void*)spec3, (void*)bufA, 1.0f, 1.0f / 256.0f);
  transpose_k<<<dim3(8, 8, 16), dim3(32, 8), 0, stream>>>(bufA, bufB, 256);
  ifft_fan_k<256><<<dim3(4096), dim3(64), 0, stream>>>(bufB, (float*)bufA, 1.0f / 256.0f, 524288);
  fs_col_d_k<<<dim3(2048), dim3(256), 0, stream>>>((float*)bufA, out1, 8, 7, 524288);
  fs_col_s_k<<<dim3(2048), dim3(256), 0, stream>>>((float*)bufA, out1, 8, 7, 524288);

  // ---- Final lowpass: out0 = ifft2(X4^T) at 128^2
  fft_rows_k<128, 1, 0><<<dim3(2048), dim3(32), 0, stream>>>((const void*)spec4, (void*)bufA, 1.0f, 1.0f / 128.0f);
  transpose_k<<<dim3(4, 4, 16), dim3(32, 8), 0, stream>>>(bufA, bufB, 128);
  fft_rows_k<128, 1, 1><<<dim3(2048), dim3(32), 0, stream>>>((const void*)bufB, (void*)out0, 1.0f, 1.0f / 128.0f);
}

// Round 4
// 792.955 us; speedup vs baseline: 1.0196x; 1.0196x over previous
//
#include <hip/hip_runtime.h>
#include <math.h>

#define PI_F 3.14159265358979323846f

__constant__ float c_pkva[12] = {
  -0.0144f, 0.0272f, -0.0526f, 0.0972f, -0.193f, 0.63f,
   0.63f, -0.193f, 0.0972f, -0.0526f, 0.0272f, -0.0144f
};

constexpr int ilog2c(int n) { int l = 0; while (n > 1) { n >>= 1; ++l; } return l; }
constexpr int fft_nt(int N) { return (N >= 512) ? N / 8 : N / 4; }
constexpr int pnc(int N) { return N + (N >> 4); }  // padded length

// Bank-conflict-avoidance padding: one float2 pad per 16.
__device__ __forceinline__ int pidx(int i) { return i + (i >> 4); }

__device__ __forceinline__ float phi_dev(int k, int n) {
  int kk = (k < n - k) ? k : (n - k);
  float w = 2.0f * PI_F * (float)kk / (float)n;
  float s = (w - PI_F / 3.0f) * (3.0f / PI_F);
  s = fminf(fmaxf(s, 0.0f), 1.0f);
  float s2 = s * s;
  float beta = s2 * s2 * (35.0f - 84.0f * s + 70.0f * s2 - 20.0f * s2 * s);
  return __cosf(0.5f * PI_F * beta);
}

__device__ __forceinline__ float2 cmul(float2 a, float2 b) {
  return make_float2(a.x * b.x - a.y * b.y, a.x * b.y + a.y * b.x);
}
__device__ __forceinline__ float2 cadd(float2 a, float2 b) { return make_float2(a.x + b.x, a.y + b.y); }
__device__ __forceinline__ float2 csub(float2 a, float2 b) { return make_float2(a.x - b.x, a.y - b.y); }

// ---------------------------------------------------------------------------
// In-LDS Stockham FFT core over padded buffer sb[2*PN]. Radix-8 (NT==N/8)
// with optional lead radix-2/4; radix-4 path (NT==N/4) for small N.
// ---------------------------------------------------------------------------
template <int N, int NT>
__device__ __forceinline__ int fft_core(float2* sb, float dirsign, int tid, int cur) {
  constexpr int LOG2 = ilog2c(N);
  constexpr int PN = pnc(N);
  if constexpr (NT == N / 8) {
    constexpr int REM = LOG2 % 3;
    if constexpr (REM == 1) {  // lead radix-2
#pragma unroll
      for (int j = tid; j < N / 2; j += NT) {
        float2 v0 = sb[cur * PN + pidx(j)];
        float2 v1 = sb[cur * PN + pidx(j + N / 2)];
        const int d = (cur ^ 1) * PN;
        sb[d + pidx(2 * j)]     = cadd(v0, v1);
        sb[d + pidx(2 * j + 1)] = csub(v0, v1);
      }
      cur ^= 1;
      __syncthreads();
    } else if constexpr (REM == 2) {  // lead radix-4
#pragma unroll
      for (int j = tid; j < N / 4; j += NT) {
        float2 v0 = sb[cur * PN + pidx(j)];
        float2 v1 = sb[cur * PN + pidx(j + N / 4)];
        float2 v2 = sb[cur * PN + pidx(j + N / 2)];
        float2 v3 = sb[cur * PN + pidx(j + 3 * (N / 4))];
        float2 a0 = cadd(v0, v2), a1 = csub(v0, v2);
        float2 a2 = cadd(v1, v3), a3 = csub(v1, v3);
        float2 r1 = make_float2(-dirsign * a3.y, dirsign * a3.x);
        const int d = (cur ^ 1) * PN;
        sb[d + pidx(4 * j)]     = cadd(a0, a2);
        sb[d + pidx(4 * j + 1)] = cadd(a1, r1);
        sb[d + pidx(4 * j + 2)] = csub(a0, a2);
        sb[d + pidx(4 * j + 3)] = csub(a1, r1);
      }
      cur ^= 1;
      __syncthreads();
    }
    constexpr int START = (REM == 1) ? 2 : ((REM == 2) ? 4 : 1);
#pragma unroll
    for (int Ns = START; Ns < N; Ns <<= 3) {
      const int j = tid;
      const int base = j & (Ns - 1);
      float ang = dirsign * (2.0f * PI_F) * (float)base / (float)(8 * Ns);
      float2 w1; __sincosf(ang, &w1.y, &w1.x);
      float2 w2 = cmul(w1, w1);
      float2 w3 = cmul(w2, w1);
      float2 w4 = cmul(w2, w2);
      float2 w5 = cmul(w3, w2);
      float2 w6 = cmul(w3, w3);
      float2 w7 = cmul(w4, w3);
      const int s = cur * PN;
      float2 u0 = sb[s + pidx(j)];
      float2 u1 = cmul(sb[s + pidx(j + (N / 8))], w1);
      float2 u2 = cmul(sb[s + pidx(j + 2 * (N / 8))], w2);
      float2 u3 = cmul(sb[s + pidx(j + 3 * (N / 8))], w3);
      float2 u4 = cmul(sb[s + pidx(j + 4 * (N / 8))], w4);
      float2 u5 = cmul(sb[s + pidx(j + 5 * (N / 8))], w5);
      float2 u6 = cmul(sb[s + pidx(j + 6 * (N / 8))], w6);
      float2 u7 = cmul(sb[s + pidx(j + 7 * (N / 8))], w7);
      float2 a0 = cadd(u0, u4), a1 = csub(u0, u4);
      float2 a2 = cadd(u2, u6), a3 = csub(u2, u6);
      float2 ra = make_float2(-dirsign * a3.y, dirsign * a3.x);
      float2 e0 = cadd(a0, a2), e1 = cadd(a1, ra), e2 = csub(a0, a2), e3 = csub(a1, ra);
      float2 b0 = cadd(u1, u5), b1 = csub(u1, u5);
      float2 b2 = cadd(u3, u7), b3 = csub(u3, u7);
      float2 rb = make_float2(-dirsign * b3.y, dirsign * b3.x);
      float2 o0 = cadd(b0, b2), o1 = cadd(b1, rb), o2 = csub(b0, b2), o3 = csub(b1, rb);
      const float C8 = 0.70710678118654752f;
      o1 = make_float2(C8 * (o1.x - dirsign * o1.y), C8 * (dirsign * o1.x + o1.y));
      o2 = make_float2(-dirsign * o2.y, dirsign * o2.x);
      o3 = make_float2(-C8 * (o3.x + dirsign * o3.y), C8 * (dirsign * o3.x - o3.y));
      int idxD = ((j - base) << 3) + base;
      cur ^= 1;
      const int d = cur * PN;
      sb[d + pidx(idxD)]          = cadd(e0, o0);
      sb[d + pidx(idxD + Ns)]     = cadd(e1, o1);
      sb[d + pidx(idxD + 2 * Ns)] = cadd(e2, o2);
      sb[d + pidx(idxD + 3 * Ns)] = cadd(e3, o3);
      sb[d + pidx(idxD + 4 * Ns)] = csub(e0, o0);
      sb[d + pidx(idxD + 5 * Ns)] = csub(e1, o1);
      sb[d + pidx(idxD + 6 * Ns)] = csub(e2, o2);
      sb[d + pidx(idxD + 7 * Ns)] = csub(e3, o3);
      __syncthreads();
    }
  } else {
    constexpr bool LEAD2 = (LOG2 & 1);
    if constexpr (LEAD2) {
#pragma unroll
      for (int j = tid; j < N / 2; j += NT) {
        float2 v0 = sb[cur * PN + pidx(j)];
        float2 v1 = sb[cur * PN + pidx(j + N / 2)];
        const int d = (cur ^ 1) * PN;
        sb[d + pidx(2 * j)]     = cadd(v0, v1);
        sb[d + pidx(2 * j + 1)] = csub(v0, v1);
      }
      cur ^= 1;
      __syncthreads();
    }
#pragma unroll
    for (int Ns = LEAD2 ? 2 : 1; Ns < N; Ns <<= 2) {
      int j = tid;
      int base = j & (Ns - 1);
      float ang = dirsign * (2.0f * PI_F) * (float)base / (float)(4 * Ns);
      float2 w1; __sincosf(ang, &w1.y, &w1.x);
      float2 w2 = cmul(w1, w1);
      float2 w3 = cmul(w2, w1);
      const int s = cur * PN;
      float2 v0 = sb[s + pidx(j)];
      float2 v1 = cmul(sb[s + pidx(j + N / 4)], w1);
      float2 v2 = cmul(sb[s + pidx(j + N / 2)], w2);
      float2 v3 = cmul(sb[s + pidx(j + 3 * (N / 4))], w3);
      float2 a0 = cadd(v0, v2), a1 = csub(v0, v2);
      float2 a2 = cadd(v1, v3), a3 = csub(v1, v3);
      float2 r1 = make_float2(-dirsign * a3.y, dirsign * a3.x);
      int idxD = ((j - base) << 2) + base;
      cur ^= 1;
      const int d = cur * PN;
      sb[d + pidx(idxD)]          = cadd(a0, a2);
      sb[d + pidx(idxD + Ns)]     = cadd(a1, r1);
      sb[d + pidx(idxD + 2 * Ns)] = csub(a0, a2);
      sb[d + pidx(idxD + 3 * Ns)] = csub(a1, r1);
      __syncthreads();
    }
  }
  return cur;
}

// ---------------------------------------------------------------------------
// Batched row FFT. LMODE: 1 = complex load, 2 = complex * Hm mask.
// SMODE: 0 = complex store, 1 = real store.
// ---------------------------------------------------------------------------
template <int N, int LMODE, int SMODE>
__global__ void __launch_bounds__(fft_nt(N))
fft_rows_k(const void* __restrict__ vin, void* __restrict__ vout,
           float dirsign, float scale) {
  constexpr int NT = fft_nt(N);
  constexpr int PN = pnc(N);
  __shared__ __align__(16) float2 sb[2 * PN];
  const int tid = threadIdx.x;
  const int row = blockIdx.x;
  const int r = row & (N - 1);

  if (LMODE == 1) {
    const float2* in = (const float2*)vin;
#pragma unroll
    for (int i = tid; i < N; i += NT) {
      float2 v = in[(size_t)row * N + i];
      sb[pidx(i)] = make_float2(v.x * scale, v.y * scale);
    }
  } else {
    const float2* in = (const float2*)vin;
    float pr = phi_dev(r, N);
#pragma unroll
    for (int i = tid; i < N; i += NT) {
      float lm = pr * phi_dev(i, N);
      float hm = sqrtf(fmaxf(1.0f - lm * lm, 0.0f));
      float m = hm * scale;
      float2 v = in[(size_t)row * N + i];
      sb[pidx(i)] = make_float2(v.x * m, v.y * m);
    }
  }
  __syncthreads();

  int cur = fft_core<N, NT>(sb, dirsign, tid, 0);

  if (SMODE == 0) {
    float2* outp = (float2*)vout;
#pragma unroll
    for (int i = tid; i < N; i += NT)
      outp[(size_t)row * N + i] = sb[cur * PN + pidx(i)];
  } else {
    float* outp = (float*)vout;
#pragma unroll
    for (int i = tid; i < N; i += NT)
      outp[(size_t)row * N + i] = sb[cur * PN + pidx(i)].x;
  }
}

// ---------------------------------------------------------------------------
// First forward FFT on real input: rows (2r, 2r+1) packed as one complex FFT.
// ---------------------------------------------------------------------------
template <int N>
__global__ void __launch_bounds__(fft_nt(N))
rfft_pairs_k(const float* __restrict__ in, float2* __restrict__ out) {
  constexpr int NT = fft_nt(N);
  constexpr int PN = pnc(N);
  __shared__ __align__(16) float2 sb[2 * PN];
  const int tid = threadIdx.x;
  const int img = blockIdx.x >> (ilog2c(N) - 1);
  const int r = blockIdx.x & (N / 2 - 1);
  const size_t row0 = (size_t)img * N + 2 * r;
  const float* p0 = in + row0 * N;
  const float* p1 = p0 + N;

#pragma unroll
  for (int i = tid; i < N; i += NT)
    sb[pidx(i)] = make_float2(p0[i], p1[i]);
  __syncthreads();

  int cur = fft_core<N, NT>(sb, -1.0f, tid, 0);

  float2* o0 = out + row0 * N;
  float2* o1 = o0 + N;
#pragma unroll
  for (int i = tid; i < N; i += NT) {
    float2 Z = sb[cur * PN + pidx(i)];
    float2 Zr = sb[cur * PN + pidx((N - i) & (N - 1))];
    float2 Zc = make_float2(Zr.x, -Zr.y);
    o0[i] = make_float2(0.5f * (Z.x + Zc.x), 0.5f * (Z.y + Zc.y));
    float2 dd = make_float2(Z.x - Zc.x, Z.y - Zc.y);
    o1[i] = make_float2(0.5f * dd.y, -0.5f * dd.x);
  }
}

// ---------------------------------------------------------------------------
// Fused level-1 column pass: forward FFT along ky, store Lm-masked ky-fold
// (for decimation), apply Hm*(1/N), inverse FFT, store in-place.
// fold layout: [img][kx][c], c < N/2.
// ---------------------------------------------------------------------------
template <int N>
__global__ void __launch_bounds__(fft_nt(N))
fft_col_fused_k(float2* __restrict__ inout, float2* __restrict__ fold) {
  constexpr int NT = fft_nt(N);
  constexpr int PN = pnc(N);
  __shared__ __align__(16) float2 sb[2 * PN];
  const int tid = threadIdx.x;
  const int row = blockIdx.x;
  const int r = row & (N - 1);  // kx

#pragma unroll
  for (int i = tid; i < N; i += NT)
    sb[pidx(i)] = inout[(size_t)row * N + i];
  __syncthreads();

  int cur = fft_core<N, NT>(sb, -1.0f, tid, 0);

  float pr = phi_dev(r, N);
  // ky-fold with Lm mask and 0.25 factor (both aliases are in this row).
#pragma unroll
  for (int i = tid; i < N / 2; i += NT) {
    float2 vA = sb[cur * PN + pidx(i)];
    float2 vB = sb[cur * PN + pidx(i + N / 2)];
    float lmA = 0.25f * pr * phi_dev(i, N);
    float lmB = 0.25f * pr * phi_dev(i + N / 2, N);
    fold[(size_t)row * (N / 2) + i] =
        make_float2(vA.x * lmA + vB.x * lmB, vA.y * lmA + vB.y * lmB);
  }
  // Hm mask in place
#pragma unroll
  for (int i = tid; i < N; i += NT) {
    float2 v = sb[cur * PN + pidx(i)];
    float lm = pr * phi_dev(i, N);
    float hm = sqrtf(fmaxf(1.0f - lm * lm, 0.0f)) * (1.0f / (float)N);
    sb[cur * PN + pidx(i)] = make_float2(v.x * hm, v.y * hm);
  }
  __syncthreads();

  cur = fft_core<N, NT>(sb, 1.0f, tid, cur);

#pragma unroll
  for (int i = tid; i < N; i += NT)
    inout[(size_t)row * N + i] = sb[cur * PN + pidx(i)];
}

// Row-fold: spec[img][r][c] = fold[img][r][c] + fold[img][r+N2][c]
__global__ void fold_rows_k(const float2* __restrict__ in,
                            float2* __restrict__ out, int lgN2) {
  int idx = blockIdx.x * 256 + threadIdx.x;
  int N2 = 1 << lgN2;
  int c = idx & (N2 - 1);
  int r = (idx >> lgN2) & (N2 - 1);
  int img = idx >> (2 * lgN2);
  size_t base = ((size_t)img << (2 * lgN2 + 1));
  float2 a = in[base + ((size_t)r << lgN2) + c];
  float2 b = in[base + ((size_t)(r + N2) << lgN2) + c];
  out[((size_t)img << (2 * lgN2)) + ((size_t)r << lgN2) + c] = cadd(a, b);
}

// ---------------------------------------------------------------------------
// Fused: inverse row FFT + first DFB fan split (axis=-1). Conflict-free
// deinterleave: contiguous LDS read, scatter-write to stride-1 cosets.
// ---------------------------------------------------------------------------
template <int N>
__global__ void __launch_bounds__(fft_nt(N))
ifft_fan_k(const float2* __restrict__ in, float* __restrict__ outb,
           float scale, int halfT) {
  constexpr int NT = fft_nt(N);
  constexpr int PN = pnc(N);
  constexpr int W2 = N / 2;
  __shared__ __align__(16) float2 sb[2 * PN];
  const int tid = threadIdx.x;
  const int nr = blockIdx.x;
  const int r = nr & (N - 1);
  const int par = r & 1;
  const float sgn = par ? -1.0f : 1.0f;

#pragma unroll
  for (int i = tid; i < N; i += NT) {
    float2 v = in[(size_t)nr * N + i];
    sb[pidx(i)] = make_float2(v.x * scale, v.y * scale);
  }
  __syncthreads();

  int cur = fft_core<N, NT>(sb, 1.0f, tid, 0);

  float* scratch = (float*)(sb + (cur ^ 1) * PN);
  float* xe = scratch;            // W2 floats
  float* xo = scratch + W2;       // W2 floats
  float* db = scratch + 2 * W2;   // W2 floats  (3*W2 fits in PN float2s)
#pragma unroll
  for (int i = tid; i < N; i += NT) {
    float v = sb[cur * PN + pidx(i)].x;
    int ii = (i - par) & (N - 1);
    if (ii & 1) xo[ii >> 1] = v; else xe[ii >> 1] = v;
  }
  __syncthreads();

  float* outs = outb + (size_t)nr * W2;
  float* outd = outb + halfT + (size_t)nr * W2;
#pragma unroll 2
  for (int j = tid; j < W2; j += NT) {
    float acc = 0.0f;
#pragma unroll
    for (int k = 0; k < 12; k++)
      acc += c_pkva[k] * xe[(j - 6 + k + W2) & (W2 - 1)];
    float dv = sgn * (xo[j] - acc);
    db[j] = dv;
    outd[j] = dv;
  }
  __syncthreads();
#pragma unroll 2
  for (int j = tid; j < W2; j += NT) {
    float acc = 0.0f;
#pragma unroll
    for (int k = 0; k < 12; k++)
      acc += c_pkva[k] * db[(j - 6 + k + W2) & (W2 - 1)];
    outs[j] = sgn * xe[j] + 0.5f * acc;
  }
}

// Batched square transpose (per-image), complex
__global__ void transpose_k(const float2* __restrict__ in,
                            float2* __restrict__ out, int N) {
  __shared__ float2 tile[32][33];
  int img = blockIdx.z;
  size_t base = (size_t)img * N * N;
  int x = blockIdx.x * 32 + threadIdx.x;
  int y0 = blockIdx.y * 32;
  for (int j = threadIdx.y; j < 32; j += 8)
    tile[j][threadIdx.x] = in[base + (size_t)(y0 + j) * N + x];
  __syncthreads();
  int x2 = blockIdx.y * 32 + threadIdx.x;
  int y2 = blockIdx.x * 32;
  for (int j = threadIdx.y; j < 32; j += 8)
    out[base + (size_t)(y2 + j) * N + x2] = tile[threadIdx.x][j];
}

// Frequency-domain decimation by 2 with Lm mask (levels 2/3).
__global__ void alias_k(const float2* __restrict__ in, float2* __restrict__ out,
                        int N, int lgN2) {
  int idx = blockIdx.x * 256 + threadIdx.x;
  int N2 = N >> 1;
  int c = idx & (N2 - 1);
  int r = (idx >> lgN2) & (N2 - 1);
  int img = idx >> (2 * lgN2);
  float pr0 = phi_dev(r, N), pr1 = phi_dev(r + N2, N);
  float pc0 = phi_dev(c, N), pc1 = phi_dev(c + N2, N);
  size_t base = (size_t)img * N * N;
  float2 v00 = in[base + (size_t)r * N + c];
  float2 v01 = in[base + (size_t)r * N + c + N2];
  float2 v10 = in[base + (size_t)(r + N2) * N + c];
  float2 v11 = in[base + (size_t)(r + N2) * N + c + N2];
  float m00 = pr0 * pc0, m01 = pr0 * pc1, m10 = pr1 * pc0, m11 = pr1 * pc1;
  float2 o;
  o.x = 0.25f * (v00.x * m00 + v01.x * m01 + v10.x * m10 + v11.x * m11);
  o.y = 0.25f * (v00.y * m00 + v01.y * m01 + v10.y * m10 + v11.y * m11);
  out[((size_t)img << (2 * lgN2)) + ((size_t)r << lgN2) + c] = o;
}

// Standalone DFB fan split, axis=-1 (mid-pipeline; W <= 512 here).
__global__ void __launch_bounds__(256)
fs_row_k(const float* __restrict__ x, float* __restrict__ outb,
         int lgH, int lgW, int halfT) {
  __shared__ float xe[512], xo[512], db[512];
  int H = 1 << lgH, W = 1 << lgW, W2 = W >> 1;
  int nr = blockIdx.x;
  int r = nr & (H - 1);
  int par = r & 1;
  float sgn = par ? -1.0f : 1.0f;
  const float* xrow = x + (size_t)nr * W;
  for (int j = threadIdx.x; j < W2; j += 256) {
    xe[j] = sgn * xrow[(2 * j + par) & (W - 1)];
    xo[j] = sgn * xrow[(2 * j + 1 + par) & (W - 1)];
  }
  __syncthreads();
  float* outs = outb + (size_t)nr * W2;
  float* outd = outb + halfT + (size_t)nr * W2;
  for (int j = threadIdx.x; j < W2; j += 256) {
    float acc = 0.0f;
#pragma unroll
    for (int k = 0; k < 12; k++)
      acc += c_pkva[k] * xe[(j - 6 + k + W2) & (W2 - 1)];
    float dv = xo[j] - acc;
    db[j] = dv;
    outd[j] = dv;
  }
  __syncthreads();
  for (int j = threadIdx.x; j < W2; j += 256) {
    float acc = 0.0f;
#pragma unroll
    for (int k = 0; k < 12; k++)
      acc += c_pkva[k] * db[(j - 6 + k + W2) & (W2 - 1)];
    outs[j] = xe[j] + 0.5f * acc;
  }
}

// DFB fan split, axis=-2: d pass.
__global__ void __launch_bounds__(256)
fs_col_d_k(const float* __restrict__ x, float* __restrict__ outb,
           int lgH, int lgW, int halfT) {
  int H = 1 << lgH, W = 1 << lgW, H2 = H >> 1;
  int idx = blockIdx.x * 256 + threadIdx.x;
  int c = idx & (W - 1);
  int i = (idx >> lgW) & (H2 - 1);
  int n = idx >> (lgW + lgH - 1);
  int par = c & 1;
  float sgn = par ? -1.0f : 1.0f;
  const float* xim = x + ((size_t)n << (lgH + lgW));
  float p1 = xim[(((2 * i + 1 + par) & (H - 1)) << lgW) + c];
  float acc = 0.0f;
#pragma unroll
  for (int k = 0; k < 12; k++) {
    int m = (i - 6 + k + H2) & (H2 - 1);
    acc += c_pkva[k] * xim[(((2 * m + par) & (H - 1)) << lgW) + c];
  }
  outb[halfT + idx] = sgn * (p1 - acc);
}

// DFB fan split, axis=-2: s pass.
__global__ void __launch_bounds__(256)
fs_col_s_k(const float* __restrict__ x, float* __restrict__ outb,
           int lgH, int lgW, int halfT) {
  int H = 1 << lgH, W = 1 << lgW, H2 = H >> 1;
  int idx = blockIdx.x * 256 + threadIdx.x;
  int c = idx & (W - 1);
  int i = (idx >> lgW) & (H2 - 1);
  int n = idx >> (lgW + lgH - 1);
  int par = c & 1;
  float sgn = par ? -1.0f : 1.0f;
  const float* xim = x + ((size_t)n << (lgH + lgW));
  float p0 = sgn * xim[(((2 * i + par) & (H - 1)) << lgW) + c];
  float acc = 0.0f;
#pragma unroll
  for (int k = 0; k < 12; k++) {
    int m = (i - 6 + k + H2) & (H2 - 1);
    acc += c_pkva[k] * outb[halfT + ((((n << (lgH - 1)) + m) << lgW) + c)];
  }
  outb[idx] = p0 + 0.5f * acc;
}

__global__ void fill_err_k(float* out) {
  out[threadIdx.x] = 1.0e9f;
}

// ---------------------------------------------------------------------------
extern "C" void kernel_launch(void* const* d_in, const int* in_sizes, int n_in,
                              void* d_out, int out_size, void* d_ws, size_t ws_size,
                              hipStream_t stream) {
  const float* x = (const float*)d_in[0];
  float* out = (float*)d_out;
  char* ws = (char*)d_ws;

  const size_t NEED = 312475648ull;
  if (ws_size < NEED) {
    fill_err_k<<<dim3(1), dim3(256), 0, stream>>>(out);
    return;
  }

  float2* bufA  = (float2*)(ws);
  float2* bufB  = (float2*)(ws + 134217728);
  float2* spec2 = (float2*)(ws + 268435456);
  float2* spec3 = (float2*)(ws + 301989888);
  float2* spec4 = (float2*)(ws + 310378496);

  float* out0 = out;             // 262144
  float* out1 = out + 262144;    // 1048576
  float* out2 = out + 1310720;   // 4194304
  float* out3 = out + 5505024;   // 16777216

  // ---- Level 1
  rfft_pairs_k<1024><<<dim3(8192), dim3(128), 0, stream>>>(x, bufA);
  transpose_k<<<dim3(32, 32, 16), dim3(32, 8), 0, stream>>>(bufA, bufB, 1024);
  // fwd col FFT -> Lm-masked ky-fold into bufA; Hm*inverse col FFT in-place
  fft_col_fused_k<1024><<<dim3(16384), dim3(128), 0, stream>>>(bufB, bufA);
  fold_rows_k<<<dim3(16384), dim3(256), 0, stream>>>(bufA, spec2, 9);
  transpose_k<<<dim3(32, 32, 16), dim3(32, 8), 0, stream>>>(bufB, bufA, 1024);
  ifft_fan_k<1024><<<dim3(16384), dim3(128), 0, stream>>>(bufA, (float*)bufB, 1.0f / 1024.0f, 8388608);
  // DFB n=4 remaining stages
  fs_col_d_k<<<dim3(32768), dim3(256), 0, stream>>>((float*)bufB, (float*)bufA, 10, 9, 8388608);
  fs_col_s_k<<<dim3(32768), dim3(256), 0, stream>>>((float*)bufB, (float*)bufA, 10, 9, 8388608);
  fs_row_k  <<<dim3(32768), dim3(256), 0, stream>>>((float*)bufA, (float*)bufB, 9, 9, 8388608);
  fs_col_d_k<<<dim3(32768), dim3(256), 0, stream>>>((float*)bufB, out3, 9, 8, 8388608);
  fs_col_s_k<<<dim3(32768), dim3(256), 0, stream>>>((float*)bufB, out3, 9, 8, 8388608);

  // ---- Level 2
  alias_k<<<dim3(4096), dim3(256), 0, stream>>>(spec2, spec3, 512, 8);
  fft_rows_k<512, 2, 0><<<dim3(8192), dim3(64), 0, stream>>>((const void*)spec2, (void*)bufA, 1.0f, 1.0f / 512.0f);
  transpose_k<<<dim3(16, 16, 16), dim3(32, 8), 0, stream>>>(bufA, bufB, 512);
  ifft_fan_k<512><<<dim3(8192), dim3(64), 0, stream>>>(bufB, (float*)bufA, 1.0f / 512.0f, 2097152);
  fs_col_d_k<<<dim3(8192),  dim3(256), 0, stream>>>((float*)bufA, (float*)bufB, 9, 8, 2097152);
  fs_col_s_k<<<dim3(8192),  dim3(256), 0, stream>>>((float*)bufA, (float*)bufB, 9, 8, 2097152);
  fs_row_k  <<<dim3(16384), dim3(256), 0, stream>>>((float*)bufB, out2, 8, 8, 2097152);

  // ---- Level 3
  alias_k<<<dim3(1024), dim3(256), 0, stream>>>(spec3, spec4, 256, 7);
  fft_rows_k<256, 2, 0><<<dim3(4096), dim3(64), 0, stream>>>((const void*)spec3, (void*)bufA, 1.0f, 1.0f / 256.0f);
  transpose_k<<<dim3(8, 8, 16), dim3(32, 8), 0, stream>>>(bufA, bufB, 256);
  ifft_fan_k<256><<<dim3(4096), dim3(64), 0, stream>>>(bufB, (float*)bufA, 1.0f / 256.0f, 524288);
  fs_col_d_k<<<dim3(2048), dim3(256), 0, stream>>>((float*)bufA, out1, 8, 7, 524288);
  fs_col_s_k<<<dim3(2048), dim3(256), 0, stream>>>((float*)bufA, out1, 8, 7, 524288);

  // ---- Final lowpass: out0 = ifft2(X4^T) at 128^2
  fft_rows_k<128, 1, 0><<<dim3(2048), dim3(32), 0, stream>>>((const void*)spec4, (void*)bufA, 1.0f, 1.0f / 128.0f);
  transpose_k<<<dim3(4, 4, 16), dim3(32, 8), 0, stream>>>(bufA, bufB, 128);
  fft_rows_k<128, 1, 1><<<dim3(2048), dim3(32), 0, stream>>>((const void*)bufB, (void*)out0, 1.0f, 1.0f / 128.0f);
}

// Round 5
// 761.624 us; speedup vs baseline: 1.0616x; 1.0411x over previous
//
#include <hip/hip_runtime.h>
#include <math.h>

#define PI_F 3.14159265358979323846f

__constant__ float c_pkva[12] = {
  -0.0144f, 0.0272f, -0.0526f, 0.0972f, -0.193f, 0.63f,
   0.63f, -0.193f, 0.0972f, -0.0526f, 0.0272f, -0.0144f
};

constexpr int ilog2c(int n) { int l = 0; while (n > 1) { n >>= 1; ++l; } return l; }

// Meyer phi lookup table: [0,1024) for N=1024, [1024,1536) N=512,
// [1536,1792) N=256, [1792,1920) N=128. Filled by phi_init_k each launch.
__device__ float g_phi[1920];
constexpr int phi_off(int N) {
  return (N == 1024) ? 0 : (N == 512) ? 1024 : (N == 256) ? 1536 : 1792;
}

__device__ __forceinline__ float phi_dev(int k, int n) {
  int kk = (k < n - k) ? k : (n - k);
  float w = 2.0f * PI_F * (float)kk / (float)n;
  float s = (w - PI_F / 3.0f) * (3.0f / PI_F);
  s = fminf(fmaxf(s, 0.0f), 1.0f);
  float s2 = s * s;
  float beta = s2 * s2 * (35.0f - 84.0f * s + 70.0f * s2 - 20.0f * s2 * s);
  return __cosf(0.5f * PI_F * beta);
}

__global__ void phi_init_k() {
  int i = blockIdx.x * 256 + threadIdx.x;
  if (i < 1024)      g_phi[i] = phi_dev(i, 1024);
  else if (i < 1536) g_phi[i] = phi_dev(i - 1024, 512);
  else if (i < 1792) g_phi[i] = phi_dev(i - 1536, 256);
  else if (i < 1920) g_phi[i] = phi_dev(i - 1792, 128);
}

__device__ __forceinline__ float2 cmul(float2 a, float2 b) {
  return make_float2(a.x * b.x - a.y * b.y, a.x * b.y + a.y * b.x);
}
__device__ __forceinline__ float2 cadd(float2 a, float2 b) { return make_float2(a.x + b.x, a.y + b.y); }
__device__ __forceinline__ float2 csub(float2 a, float2 b) { return make_float2(a.x - b.x, a.y - b.y); }

// ---------------------------------------------------------------------------
// In-LDS Stockham radix-4 FFT core (unpadded — round-2 proven). NT = N/4.
// Optional lead radix-2 when log2(N) odd (conflict-free float4 store).
// Caller syncs after filling sbuf[cur]. Returns final buffer index.
// ---------------------------------------------------------------------------
template <int N>
__device__ __forceinline__ int fft_core4(float2 (*sbuf)[N], float dirsign, int tid, int cur) {
  constexpr int LOG2 = ilog2c(N);
  constexpr int NT = N / 4;
  constexpr bool LEAD2 = (LOG2 & 1);
  if constexpr (LEAD2) {
#pragma unroll
    for (int j = tid; j < N / 2; j += NT) {
      float2 v0 = sbuf[cur][j], v1 = sbuf[cur][j + N / 2];
      float2 e = cadd(v0, v1), o = csub(v0, v1);
      *(float4*)&sbuf[cur ^ 1][2 * j] = make_float4(e.x, e.y, o.x, o.y);
    }
    cur ^= 1;
    __syncthreads();
  }
#pragma unroll
  for (int Ns = LEAD2 ? 2 : 1; Ns < N; Ns <<= 2) {
    int j = tid;
    int base = j & (Ns - 1);
    float ang = dirsign * (2.0f * PI_F) * (float)base / (float)(4 * Ns);
    float2 w1; __sincosf(ang, &w1.y, &w1.x);
    float2 w2 = cmul(w1, w1);
    float2 w3 = cmul(w2, w1);
    float2 v0 = sbuf[cur][j];
    float2 v1 = cmul(sbuf[cur][j + N / 4], w1);
    float2 v2 = cmul(sbuf[cur][j + N / 2], w2);
    float2 v3 = cmul(sbuf[cur][j + 3 * (N / 4)], w3);
    float2 a0 = cadd(v0, v2), a1 = csub(v0, v2);
    float2 a2 = cadd(v1, v3), a3 = csub(v1, v3);
    float2 r1 = make_float2(-dirsign * a3.y, dirsign * a3.x);
    int idxD = ((j - base) << 2) + base;
    cur ^= 1;
    sbuf[cur][idxD]          = cadd(a0, a2);
    sbuf[cur][idxD + Ns]     = cadd(a1, r1);
    sbuf[cur][idxD + 2 * Ns] = csub(a0, a2);
    sbuf[cur][idxD + 3 * Ns] = csub(a1, r1);
    __syncthreads();
  }
  return cur;
}

// ---------------------------------------------------------------------------
// Batched row FFT. LMODE: 1 = complex load, 2 = complex * Hm mask (table).
// SMODE: 0 = complex store, 1 = real store.
// ---------------------------------------------------------------------------
template <int N, int LMODE, int SMODE>
__global__ void __launch_bounds__(N / 4)
fft_rows_k(const void* __restrict__ vin, void* __restrict__ vout,
           float dirsign, float scale) {
  constexpr int NT = N / 4;
  __shared__ __align__(16) float2 sbuf[2][N];
  const int tid = threadIdx.x;
  const int row = blockIdx.x;
  const int r = row & (N - 1);

  if (LMODE == 1) {
    const float2* in = (const float2*)vin;
#pragma unroll
    for (int i = tid; i < N; i += NT) {
      float2 v = in[(size_t)row * N + i];
      sbuf[0][i] = make_float2(v.x * scale, v.y * scale);
    }
  } else {
    const float2* in = (const float2*)vin;
    float pr = g_phi[phi_off(N) + r];
#pragma unroll
    for (int i = tid; i < N; i += NT) {
      float lm = pr * g_phi[phi_off(N) + i];
      float m = sqrtf(fmaxf(1.0f - lm * lm, 0.0f)) * scale;
      float2 v = in[(size_t)row * N + i];
      sbuf[0][i] = make_float2(v.x * m, v.y * m);
    }
  }
  __syncthreads();

  int cur = fft_core4<N>(sbuf, dirsign, tid, 0);

  if (SMODE == 0) {
    float2* outp = (float2*)vout;
#pragma unroll
    for (int i = tid; i < N; i += NT)
      outp[(size_t)row * N + i] = sbuf[cur][i];
  } else {
    float* outp = (float*)vout;
#pragma unroll
    for (int i = tid; i < N; i += NT)
      outp[(size_t)row * N + i] = sbuf[cur][i].x;
  }
}

// ---------------------------------------------------------------------------
// First forward FFT on real input: rows (2r, 2r+1) packed as one complex FFT,
// untangled via Hermitian symmetry.
// ---------------------------------------------------------------------------
template <int N>
__global__ void __launch_bounds__(N / 4)
rfft_pairs_k(const float* __restrict__ in, float2* __restrict__ out) {
  constexpr int NT = N / 4;
  __shared__ __align__(16) float2 sbuf[2][N];
  const int tid = threadIdx.x;
  const int img = blockIdx.x >> (ilog2c(N) - 1);
  const int r = blockIdx.x & (N / 2 - 1);
  const size_t row0 = (size_t)img * N + 2 * r;
  const float* p0 = in + row0 * N;
  const float* p1 = p0 + N;

#pragma unroll
  for (int i = tid; i < N; i += NT)
    sbuf[0][i] = make_float2(p0[i], p1[i]);
  __syncthreads();

  int cur = fft_core4<N>(sbuf, -1.0f, tid, 0);

  float2* o0 = out + row0 * N;
  float2* o1 = o0 + N;
#pragma unroll
  for (int i = tid; i < N; i += NT) {
    float2 Z = sbuf[cur][i];
    float2 Zr = sbuf[cur][(N - i) & (N - 1)];
    float2 Zc = make_float2(Zr.x, -Zr.y);
    o0[i] = make_float2(0.5f * (Z.x + Zc.x), 0.5f * (Z.y + Zc.y));
    float2 dd = make_float2(Z.x - Zc.x, Z.y - Zc.y);
    o1[i] = make_float2(0.5f * dd.y, -0.5f * dd.x);
  }
}

// ---------------------------------------------------------------------------
// Fused level-1 column pass: forward FFT along ky, merged {Lm-masked ky-fold
// store + Hm mask in place}, inverse FFT, store in-place.
// fold layout: [img][kx][c], c < N/2.
// ---------------------------------------------------------------------------
template <int N>
__global__ void __launch_bounds__(N / 4)
fft_col_fused_k(float2* __restrict__ inout, float2* __restrict__ fold) {
  constexpr int NT = N / 4;
  __shared__ __align__(16) float2 sbuf[2][N];
  const int tid = threadIdx.x;
  const int row = blockIdx.x;
  const int r = row & (N - 1);  // kx

#pragma unroll
  for (int i = tid; i < N; i += NT)
    sbuf[0][i] = inout[(size_t)row * N + i];
  __syncthreads();

  int cur = fft_core4<N>(sbuf, -1.0f, tid, 0);

  const float pr = g_phi[phi_off(N) + r];
  const float inv = 1.0f / (float)N;
#pragma unroll
  for (int i = tid; i < N / 2; i += NT) {
    float2 vA = sbuf[cur][i];
    float2 vB = sbuf[cur][i + N / 2];
    float lmA = pr * g_phi[phi_off(N) + i];
    float lmB = pr * g_phi[phi_off(N) + i + N / 2];
    fold[(size_t)row * (N / 2) + i] = make_float2(
        0.25f * (vA.x * lmA + vB.x * lmB), 0.25f * (vA.y * lmA + vB.y * lmB));
    float hmA = sqrtf(fmaxf(1.0f - lmA * lmA, 0.0f)) * inv;
    float hmB = sqrtf(fmaxf(1.0f - lmB * lmB, 0.0f)) * inv;
    sbuf[cur][i]         = make_float2(vA.x * hmA, vA.y * hmA);
    sbuf[cur][i + N / 2] = make_float2(vB.x * hmB, vB.y * hmB);
  }
  __syncthreads();

  cur = fft_core4<N>(sbuf, 1.0f, tid, cur);

#pragma unroll
  for (int i = tid; i < N; i += NT)
    inout[(size_t)row * N + i] = sbuf[cur][i];
}

// Row-fold: spec[img][r][c] = fold[img][r][c] + fold[img][r+N2][c]
__global__ void fold_rows_k(const float2* __restrict__ in,
                            float2* __restrict__ out, int lgN2) {
  int idx = blockIdx.x * 256 + threadIdx.x;
  int N2 = 1 << lgN2;
  int c = idx & (N2 - 1);
  int r = (idx >> lgN2) & (N2 - 1);
  int img = idx >> (2 * lgN2);
  size_t base = ((size_t)img << (2 * lgN2 + 1));
  float2 a = in[base + ((size_t)r << lgN2) + c];
  float2 b = in[base + ((size_t)(r + N2) << lgN2) + c];
  out[((size_t)img << (2 * lgN2)) + ((size_t)r << lgN2) + c] = cadd(a, b);
}

// ---------------------------------------------------------------------------
// Fused: inverse row FFT + first DFB fan split (axis=-1). Conflict-free
// deinterleave: contiguous LDS read, scatter-write to stride-1 cosets.
// ---------------------------------------------------------------------------
template <int N>
__global__ void __launch_bounds__(N / 4)
ifft_fan_k(const float2* __restrict__ in, float* __restrict__ outb,
           float scale, int halfT) {
  constexpr int NT = N / 4;
  constexpr int W2 = N / 2;
  __shared__ __align__(16) float2 sbuf[2][N];
  const int tid = threadIdx.x;
  const int nr = blockIdx.x;
  const int r = nr & (N - 1);
  const int par = r & 1;
  const float sgn = par ? -1.0f : 1.0f;

#pragma unroll
  for (int i = tid; i < N; i += NT) {
    float2 v = in[(size_t)nr * N + i];
    sbuf[0][i] = make_float2(v.x * scale, v.y * scale);
  }
  __syncthreads();

  int cur = fft_core4<N>(sbuf, 1.0f, tid, 0);

  float* scratch = (float*)sbuf[cur ^ 1];
  float* xe = scratch;            // W2 floats
  float* xo = scratch + W2;       // W2 floats
  float* db = scratch + 2 * W2;   // W2 floats (3*W2 <= 2N floats)
#pragma unroll
  for (int i = tid; i < N; i += NT) {
    float v = sbuf[cur][i].x;
    int ii = (i - par) & (N - 1);
    if (ii & 1) xo[ii >> 1] = v; else xe[ii >> 1] = v;
  }
  __syncthreads();

  float* outs = outb + (size_t)nr * W2;
  float* outd = outb + halfT + (size_t)nr * W2;
#pragma unroll 2
  for (int j = tid; j < W2; j += NT) {
    float acc = 0.0f;
#pragma unroll
    for (int k = 0; k < 12; k++)
      acc += c_pkva[k] * xe[(j - 6 + k + W2) & (W2 - 1)];
    float dv = sgn * (xo[j] - acc);
    db[j] = dv;
    outd[j] = dv;
  }
  __syncthreads();
#pragma unroll 2
  for (int j = tid; j < W2; j += NT) {
    float acc = 0.0f;
#pragma unroll
    for (int k = 0; k < 12; k++)
      acc += c_pkva[k] * db[(j - 6 + k + W2) & (W2 - 1)];
    outs[j] = sgn * xe[j] + 0.5f * acc;
  }
}

// Batched square transpose (per-image), complex
__global__ void transpose_k(const float2* __restrict__ in,
                            float2* __restrict__ out, int N) {
  __shared__ float2 tile[32][33];
  int img = blockIdx.z;
  size_t base = (size_t)img * N * N;
  int x = blockIdx.x * 32 + threadIdx.x;
  int y0 = blockIdx.y * 32;
  for (int j = threadIdx.y; j < 32; j += 8)
    tile[j][threadIdx.x] = in[base + (size_t)(y0 + j) * N + x];
  __syncthreads();
  int x2 = blockIdx.y * 32 + threadIdx.x;
  int y2 = blockIdx.x * 32;
  for (int j = threadIdx.y; j < 32; j += 8)
    out[base + (size_t)(y2 + j) * N + x2] = tile[threadIdx.x][j];
}

// Frequency-domain decimation by 2 with Lm mask (levels 2/3), table-driven.
__global__ void alias_k(const float2* __restrict__ in, float2* __restrict__ out,
                        int N, int lgN2, int phiOff) {
  int idx = blockIdx.x * 256 + threadIdx.x;
  int N2 = N >> 1;
  int c = idx & (N2 - 1);
  int r = (idx >> lgN2) & (N2 - 1);
  int img = idx >> (2 * lgN2);
  float pr0 = g_phi[phiOff + r], pr1 = g_phi[phiOff + r + N2];
  float pc0 = g_phi[phiOff + c], pc1 = g_phi[phiOff + c + N2];
  size_t base = (size_t)img * N * N;
  float2 v00 = in[base + (size_t)r * N + c];
  float2 v01 = in[base + (size_t)r * N + c + N2];
  float2 v10 = in[base + (size_t)(r + N2) * N + c];
  float2 v11 = in[base + (size_t)(r + N2) * N + c + N2];
  float m00 = pr0 * pc0, m01 = pr0 * pc1, m10 = pr1 * pc0, m11 = pr1 * pc1;
  float2 o;
  o.x = 0.25f * (v00.x * m00 + v01.x * m01 + v10.x * m10 + v11.x * m11);
  o.y = 0.25f * (v00.y * m00 + v01.y * m01 + v10.y * m10 + v11.y * m11);
  out[((size_t)img << (2 * lgN2)) + ((size_t)r << lgN2) + c] = o;
}

// Standalone DFB fan split, axis=-1 (mid-pipeline; W <= 512 here).
__global__ void __launch_bounds__(256)
fs_row_k(const float* __restrict__ x, float* __restrict__ outb,
         int lgH, int lgW, int halfT) {
  __shared__ float xe[512], xo[512], db[512];
  int H = 1 << lgH, W = 1 << lgW, W2 = W >> 1;
  int nr = blockIdx.x;
  int r = nr & (H - 1);
  int par = r & 1;
  float sgn = par ? -1.0f : 1.0f;
  const float* xrow = x + (size_t)nr * W;
  for (int j = threadIdx.x; j < W2; j += 256) {
    xe[j] = sgn * xrow[(2 * j + par) & (W - 1)];
    xo[j] = sgn * xrow[(2 * j + 1 + par) & (W - 1)];
  }
  __syncthreads();
  float* outs = outb + (size_t)nr * W2;
  float* outd = outb + halfT + (size_t)nr * W2;
  for (int j = threadIdx.x; j < W2; j += 256) {
    float acc = 0.0f;
#pragma unroll
    for (int k = 0; k < 12; k++)
      acc += c_pkva[k] * xe[(j - 6 + k + W2) & (W2 - 1)];
    float dv = xo[j] - acc;
    db[j] = dv;
    outd[j] = dv;
  }
  __syncthreads();
  for (int j = threadIdx.x; j < W2; j += 256) {
    float acc = 0.0f;
#pragma unroll
    for (int k = 0; k < 12; k++)
      acc += c_pkva[k] * db[(j - 6 + k + W2) & (W2 - 1)];
    outs[j] = xe[j] + 0.5f * acc;
  }
}

// DFB fan split, axis=-2: d pass.
__global__ void __launch_bounds__(256)
fs_col_d_k(const float* __restrict__ x, float* __restrict__ outb,
           int lgH, int lgW, int halfT) {
  int H = 1 << lgH, W = 1 << lgW, H2 = H >> 1;
  int idx = blockIdx.x * 256 + threadIdx.x;
  int c = idx & (W - 1);
  int i = (idx >> lgW) & (H2 - 1);
  int n = idx >> (lgW + lgH - 1);
  int par = c & 1;
  float sgn = par ? -1.0f : 1.0f;
  const float* xim = x + ((size_t)n << (lgH + lgW));
  float p1 = xim[(((2 * i + 1 + par) & (H - 1)) << lgW) + c];
  float acc = 0.0f;
#pragma unroll
  for (int k = 0; k < 12; k++) {
    int m = (i - 6 + k + H2) & (H2 - 1);
    acc += c_pkva[k] * xim[(((2 * m + par) & (H - 1)) << lgW) + c];
  }
  outb[halfT + idx] = sgn * (p1 - acc);
}

// DFB fan split, axis=-2: s pass.
__global__ void __launch_bounds__(256)
fs_col_s_k(const float* __restrict__ x, float* __restrict__ outb,
           int lgH, int lgW, int halfT) {
  int H = 1 << lgH, W = 1 << lgW, H2 = H >> 1;
  int idx = blockIdx.x * 256 + threadIdx.x;
  int c = idx & (W - 1);
  int i = (idx >> lgW) & (H2 - 1);
  int n = idx >> (lgW + lgH - 1);
  int par = c & 1;
  float sgn = par ? -1.0f : 1.0f;
  const float* xim = x + ((size_t)n << (lgH + lgW));
  float p0 = sgn * xim[(((2 * i + par) & (H - 1)) << lgW) + c];
  float acc = 0.0f;
#pragma unroll
  for (int k = 0; k < 12; k++) {
    int m = (i - 6 + k + H2) & (H2 - 1);
    acc += c_pkva[k] * outb[halfT + ((((n << (lgH - 1)) + m) << lgW) + c)];
  }
  outb[idx] = p0 + 0.5f * acc;
}

__global__ void fill_err_k(float* out) {
  out[threadIdx.x] = 1.0e9f;
}

// ---------------------------------------------------------------------------
extern "C" void kernel_launch(void* const* d_in, const int* in_sizes, int n_in,
                              void* d_out, int out_size, void* d_ws, size_t ws_size,
                              hipStream_t stream) {
  const float* x = (const float*)d_in[0];
  float* out = (float*)d_out;
  char* ws = (char*)d_ws;

  const size_t NEED = 312475648ull;
  if (ws_size < NEED) {
    fill_err_k<<<dim3(1), dim3(256), 0, stream>>>(out);
    return;
  }

  float2* bufA  = (float2*)(ws);
  float2* bufB  = (float2*)(ws + 134217728);
  float2* spec2 = (float2*)(ws + 268435456);
  float2* spec3 = (float2*)(ws + 301989888);
  float2* spec4 = (float2*)(ws + 310378496);

  float* out0 = out;             // 262144
  float* out1 = out + 262144;    // 1048576
  float* out2 = out + 1310720;   // 4194304
  float* out3 = out + 5505024;   // 16777216

  phi_init_k<<<dim3(8), dim3(256), 0, stream>>>();

  // ---- Level 1
  rfft_pairs_k<1024><<<dim3(8192), dim3(256), 0, stream>>>(x, bufA);
  transpose_k<<<dim3(32, 32, 16), dim3(32, 8), 0, stream>>>(bufA, bufB, 1024);
  // fwd col FFT -> Lm-masked ky-fold into bufA; Hm*inverse col FFT in-place
  fft_col_fused_k<1024><<<dim3(16384), dim3(256), 0, stream>>>(bufB, bufA);
  fold_rows_k<<<dim3(16384), dim3(256), 0, stream>>>(bufA, spec2, 9);
  transpose_k<<<dim3(32, 32, 16), dim3(32, 8), 0, stream>>>(bufB, bufA, 1024);
  ifft_fan_k<1024><<<dim3(16384), dim3(256), 0, stream>>>(bufA, (float*)bufB, 1.0f / 1024.0f, 8388608);
  // DFB n=4 remaining stages
  fs_col_d_k<<<dim3(32768), dim3(256), 0, stream>>>((float*)bufB, (float*)bufA, 10, 9, 8388608);
  fs_col_s_k<<<dim3(32768), dim3(256), 0, stream>>>((float*)bufB, (float*)bufA, 10, 9, 8388608);
  fs_row_k  <<<dim3(32768), dim3(256), 0, stream>>>((float*)bufA, (float*)bufB, 9, 9, 8388608);
  fs_col_d_k<<<dim3(32768), dim3(256), 0, stream>>>((float*)bufB, out3, 9, 8, 8388608);
  fs_col_s_k<<<dim3(32768), dim3(256), 0, stream>>>((float*)bufB, out3, 9, 8, 8388608);

  // ---- Level 2
  alias_k<<<dim3(4096), dim3(256), 0, stream>>>(spec2, spec3, 512, 8, phi_off(512));
  fft_rows_k<512, 2, 0><<<dim3(8192), dim3(128), 0, stream>>>((const void*)spec2, (void*)bufA, 1.0f, 1.0f / 512.0f);
  transpose_k<<<dim3(16, 16, 16), dim3(32, 8), 0, stream>>>(bufA, bufB, 512);
  ifft_fan_k<512><<<dim3(8192), dim3(128), 0, stream>>>(bufB, (float*)bufA, 1.0f / 512.0f, 2097152);
  fs_col_d_k<<<dim3(8192),  dim3(256), 0, stream>>>((float*)bufA, (float*)bufB, 9, 8, 2097152);
  fs_col_s_k<<<dim3(8192),  dim3(256), 0, stream>>>((float*)bufA, (float*)bufB, 9, 8, 2097152);
  fs_row_k  <<<dim3(16384), dim3(256), 0, stream>>>((float*)bufB, out2, 8, 8, 2097152);

  // ---- Level 3
  alias_k<<<dim3(1024), dim3(256), 0, stream>>>(spec3, spec4, 256, 7, phi_off(256));
  fft_rows_k<256, 2, 0><<<dim3(4096), dim3(64), 0, stream>>>((const void*)spec3, (void*)bufA, 1.0f, 1.0f / 256.0f);
  transpose_k<<<dim3(8, 8, 16), dim3(32, 8), 0, stream>>>(bufA, bufB, 256);
  ifft_fan_k<256><<<dim3(4096), dim3(64), 0, stream>>>(bufB, (float*)bufA, 1.0f / 256.0f, 524288);
  fs_col_d_k<<<dim3(2048), dim3(256), 0, stream>>>((float*)bufA, out1, 8, 7, 524288);
  fs_col_s_k<<<dim3(2048), dim3(256), 0, stream>>>((float*)bufA, out1, 8, 7, 524288);

  // ---- Final lowpass: out0 = ifft2(X4^T) at 128^2
  fft_rows_k<128, 1, 0><<<dim3(2048), dim3(32), 0, stream>>>((const void*)spec4, (void*)bufA, 1.0f, 1.0f / 128.0f);
  transpose_k<<<dim3(4, 4, 16), dim3(32, 8), 0, stream>>>(bufA, bufB, 128);
  fft_rows_k<128, 1, 1><<<dim3(2048), dim3(32), 0, stream>>>((const void*)bufB, (void*)out0, 1.0f, 1.0f / 128.0f);
}